// Round 1
// baseline (233.870 us; speedup 1.0000x reference)
//
#include <hip/hip_runtime.h>
#include <hip/hip_bf16.h>

// Problem: B=4, L=4096, D=1024, M_MAX=512
// out[b,l,e] = smoothed[b, pbi[b,l], e] + sum_d enc[b,l,d] * W[e,d]
// (ste_c == 1.0 exactly in forward, so upsampled == plugback)

#define B_  4
#define L_  4096
#define D_  1024
#define M_  512

typedef __attribute__((ext_vector_type(8))) short bf16x8;
typedef __attribute__((ext_vector_type(4))) float f32x4;
typedef __attribute__((ext_vector_type(8))) unsigned short u16x8;

__device__ inline unsigned short f2bf(float f) {
    unsigned u = __float_as_uint(f);
    u += 0x7fffu + ((u >> 16) & 1u);   // round-to-nearest-even
    return (unsigned short)(u >> 16);
}

// ---------------- Kernel 1: W (D x D fp32) -> bf16 ----------------
__global__ void wconv_kernel(const float* __restrict__ W, unsigned short* __restrict__ Wb) {
    int i = blockIdx.x * 256 + threadIdx.x;          // each handles 4 floats
    float4 x = ((const float4*)W)[i];
    ushort4 v;
    v.x = f2bf(x.x); v.y = f2bf(x.y); v.z = f2bf(x.z); v.w = f2bf(x.w);
    ((ushort4*)Wb)[i] = v;
}

// ---------------- Kernel 2: EMA smoothing scan over M ----------------
// h_0 = c_0 ; h_m = max(1-p_m,1e-7)*h_{m-1} + p_m*c_m,  p_m = max(probs[b, idx[b,m]], 0.1)
__global__ void ema_kernel(const float* __restrict__ ct, const float* __restrict__ probs,
                           const int* __restrict__ bidx, float* __restrict__ smoothed) {
    int b = blockIdx.y;
    int d = blockIdx.x * 256 + threadIdx.x;
    __shared__ float p[M_];
    for (int m = threadIdx.x; m < M_; m += 256) {
        int idx = bidx[b * M_ + m];
        p[m] = fmaxf(probs[b * L_ + idx], 0.1f);
    }
    __syncthreads();
    const float* ctb = ct + (size_t)b * M_ * D_ + d;
    float*       smb = smoothed + (size_t)b * M_ * D_ + d;
    float h = ctb[0];
    smb[0] = h;
    for (int m = 1; m < M_; ++m) {
        float pm = p[m];
        float decay = fmaxf(1.0f - pm, 1e-7f);
        h = decay * h + pm * ctb[(size_t)m * D_];
        smb[(size_t)m * D_] = h;
    }
}

// ---------------- Kernel 3: plug_back_idx = clip(cumsum(probs>=0.5)-1, 0) ----------------
__global__ void pbi_kernel(const float* __restrict__ probs, int* __restrict__ pbi) {
    int b = blockIdx.x;
    int t = threadIdx.x;
    __shared__ int part[256];
    int base = b * L_ + t * 16;
    int cnt[16];
    int s = 0;
    #pragma unroll
    for (int i = 0; i < 16; ++i) {
        s += (probs[base + i] >= 0.5f) ? 1 : 0;
        cnt[i] = s;
    }
    part[t] = s;
    __syncthreads();
    // Hillis-Steele inclusive scan over 256 partials
    for (int off = 1; off < 256; off <<= 1) {
        int x = part[t];
        int y = (t >= off) ? part[t - off] : 0;
        __syncthreads();
        part[t] = x + y;
        __syncthreads();
    }
    int excl = part[t] - s;
    #pragma unroll
    for (int i = 0; i < 16; ++i) {
        int v = excl + cnt[i] - 1;
        pbi[base + i] = v > 0 ? v : 0;
    }
}

// ---------------- Kernel 4: fused GEMM + plugback add ----------------
// out[row, e] = acc(row, e) + smoothed[b, pbi[row], e],  row = b*L + l
// A = enc (fp32, converted to bf16 on stage), B = Wb (bf16), MFMA 16x16x32
#define BM 128
#define BN 128
#define BK 64
#define LDP 72   // padded LDS row stride (ushorts)

__global__ __launch_bounds__(256, 2) void gemm_kernel(
    const float* __restrict__ enc, const unsigned short* __restrict__ Wb,
    const float* __restrict__ smoothed, const int* __restrict__ pbi,
    float* __restrict__ out)
{
    __shared__ unsigned short As[BM][LDP];
    __shared__ unsigned short Bs[BN][LDP];

    const int tid  = threadIdx.x;
    const int lane = tid & 63;
    const int wid  = tid >> 6;
    const int wm   = wid >> 1;   // wave row (0..1)
    const int wn   = wid & 1;    // wave col (0..1)
    const int l15  = lane & 15;
    const int l16  = lane >> 4;

    const size_t rowBase = (size_t)blockIdx.x * BM;
    const int    colBase = blockIdx.y * BN;

    f32x4 acc[4][4] = {};

    for (int t = 0; t < D_ / BK; ++t) {
        const int k0 = t * BK;
        // ---- stage A (128x64 fp32 -> bf16) ----
        #pragma unroll
        for (int i = 0; i < 4; ++i) {
            int c  = i * 256 + tid;
            int r  = c >> 3;
            int c8 = c & 7;
            const float4* g = (const float4*)(enc + (rowBase + r) * D_ + k0 + c8 * 8);
            float4 x0 = g[0];
            float4 x1 = g[1];
            u16x8 v;
            v[0] = f2bf(x0.x); v[1] = f2bf(x0.y); v[2] = f2bf(x0.z); v[3] = f2bf(x0.w);
            v[4] = f2bf(x1.x); v[5] = f2bf(x1.y); v[6] = f2bf(x1.z); v[7] = f2bf(x1.w);
            *(u16x8*)&As[r][c8 * 8] = v;
        }
        // ---- stage B (128x64 bf16 rows of W) ----
        #pragma unroll
        for (int i = 0; i < 4; ++i) {
            int c  = i * 256 + tid;
            int r  = c >> 3;
            int c8 = c & 7;
            u16x8 v = *(const u16x8*)(Wb + (size_t)(colBase + r) * D_ + k0 + c8 * 8);
            *(u16x8*)&Bs[r][c8 * 8] = v;
        }
        __syncthreads();
        // ---- MFMA on the tile ----
        #pragma unroll
        for (int kk = 0; kk < 2; ++kk) {
            bf16x8 a[4], bb[4];
            #pragma unroll
            for (int m = 0; m < 4; ++m)
                a[m] = *(const bf16x8*)&As[wm * 64 + m * 16 + l15][kk * 32 + l16 * 8];
            #pragma unroll
            for (int n = 0; n < 4; ++n)
                bb[n] = *(const bf16x8*)&Bs[wn * 64 + n * 16 + l15][kk * 32 + l16 * 8];
            #pragma unroll
            for (int m = 0; m < 4; ++m)
                #pragma unroll
                for (int n = 0; n < 4; ++n)
                    acc[m][n] = __builtin_amdgcn_mfma_f32_16x16x32_bf16(a[m], bb[n], acc[m][n], 0, 0, 0);
        }
        __syncthreads();
    }

    // ---- epilogue: add plugback and store ----
    #pragma unroll
    for (int m = 0; m < 4; ++m) {
        #pragma unroll
        for (int j = 0; j < 4; ++j) {
            size_t row = rowBase + wm * 64 + m * 16 + l16 * 4 + j;
            int b  = (int)(row >> 12);             // row / L_
            int pb = pbi[row];
            pb = pb < (M_ - 1) ? pb : (M_ - 1);
            const float* sm = smoothed + ((size_t)(b * M_ + pb)) * D_;
            #pragma unroll
            for (int n = 0; n < 4; ++n) {
                int col = colBase + wn * 64 + n * 16 + l15;
                out[row * D_ + col] = acc[m][n][j] + sm[col];
            }
        }
    }
}

extern "C" void kernel_launch(void* const* d_in, const int* in_sizes, int n_in,
                              void* d_out, int out_size, void* d_ws, size_t ws_size,
                              hipStream_t stream) {
    const float* ct    = (const float*)d_in[0];   // concept_tokens (B,M,D)
    const float* enc   = (const float*)d_in[1];   // encoder_out   (B,L,D)
    const float* probs = (const float*)d_in[2];   // boundary_probs(B,L)
    const int*   bidx  = (const int*)d_in[3];     // boundary_idx  (B,M) int32
    // d_in[4] = concept_mask, all-true -> ignored
    const float* W     = (const float*)d_in[5];   // W (D,D)

    float* out = (float*)d_out;
    char*  ws  = (char*)d_ws;
    float*          smoothed = (float*)ws;                                   // 8 MiB
    int*            pbi      = (int*)(ws + (size_t)8 * 1024 * 1024);         // 64 KiB
    unsigned short* Wb       = (unsigned short*)(ws + (size_t)8 * 1024 * 1024 + 64 * 1024); // 2 MiB

    hipLaunchKernelGGL(wconv_kernel, dim3(D_ * D_ / 1024), dim3(256), 0, stream, W, Wb);
    hipLaunchKernelGGL(ema_kernel,   dim3(D_ / 256, B_),   dim3(256), 0, stream, ct, probs, bidx, smoothed);
    hipLaunchKernelGGL(pbi_kernel,   dim3(B_),             dim3(256), 0, stream, probs, pbi);
    hipLaunchKernelGGL(gemm_kernel,  dim3(B_ * L_ / BM, D_ / BN), dim3(256), 0, stream,
                       enc, Wb, smoothed, pbi, out);
}

// Round 2
// 186.317 us; speedup vs baseline: 1.2552x; 1.2552x over previous
//
#include <hip/hip_runtime.h>
#include <hip/hip_bf16.h>
#include <stdint.h>

// Problem: B=4, L=4096, D=1024, M_MAX=512
// out[b,l,e] = smoothed[b, pbi[b,l], e] + sum_d enc[b,l,d] * W[e,d]
// (ste_c == 1.0 exactly in forward, so upsampled == plugback)

#define B_  4
#define L_  4096
#define D_  1024
#define M_  512

typedef __attribute__((ext_vector_type(8))) short bf16x8;
typedef __attribute__((ext_vector_type(4))) float f32x4;
typedef __attribute__((ext_vector_type(8))) unsigned short u16x8;

__device__ inline unsigned short f2bf(float f) {
    unsigned u = __float_as_uint(f);
    u += 0x7fffu + ((u >> 16) & 1u);   // round-to-nearest-even
    return (unsigned short)(u >> 16);
}

// ---------------- fp32 -> bf16 streaming convert (8 elems/thread) ----------------
__global__ void cvt_kernel(const float* __restrict__ in, unsigned short* __restrict__ out) {
    int i = blockIdx.x * 256 + threadIdx.x;
    float4 x0 = ((const float4*)in)[2 * i];
    float4 x1 = ((const float4*)in)[2 * i + 1];
    u16x8 v;
    v[0] = f2bf(x0.x); v[1] = f2bf(x0.y); v[2] = f2bf(x0.z); v[3] = f2bf(x0.w);
    v[4] = f2bf(x1.x); v[5] = f2bf(x1.y); v[6] = f2bf(x1.z); v[7] = f2bf(x1.w);
    ((u16x8*)out)[i] = v;
}

// ---------------- EMA smoothing: chunked affine scan ----------------
// h_m = a_m*h_{m-1} + b_m ; a_0=0,b_0=c_0 ; a_m=max(1-p_m,1e-7), b_m=p_m*c_m
// block: 512 threads = 64 d-lanes x 8 chunks of 64 m's. grid: B * D/64.
__global__ void ema_kernel(const float* __restrict__ ct, const float* __restrict__ probs,
                           const int* __restrict__ bidx, float* __restrict__ smoothed) {
    int b  = blockIdx.x >> 4;
    int d0 = (blockIdx.x & 15) * 64;
    int t  = threadIdx.x;
    int dl = t & 63;
    int ch = t >> 6;                      // 0..7
    __shared__ float ad[M_], bdp[M_];
    __shared__ float Ac[8][64], Bc[8][64], Hin[8][64];
    for (int m = t; m < M_; m += 512) {
        int idx = bidx[b * M_ + m];
        float p = fmaxf(probs[b * L_ + idx], 0.1f);
        ad[m]  = (m == 0) ? 0.0f : fmaxf(1.0f - p, 1e-7f);
        bdp[m] = (m == 0) ? 1.0f : p;
    }
    __syncthreads();
    const float* ctp = ct + ((size_t)b * M_ + ch * 64) * D_ + d0 + dl;
    float A = 1.0f, Bv = 0.0f;
    #pragma unroll 8
    for (int i = 0; i < 64; ++i) {
        int m = ch * 64 + i;
        float c = ctp[(size_t)i * D_];
        A  = ad[m] * A;
        Bv = ad[m] * Bv + bdp[m] * c;
    }
    Ac[ch][dl] = A; Bc[ch][dl] = Bv;
    __syncthreads();
    if (t < 64) {                          // per-d prefix over 8 chunk summaries
        float H = 0.0f;
        #pragma unroll
        for (int c = 0; c < 8; ++c) {
            Hin[c][t] = H;
            H = Ac[c][t] * H + Bc[c][t];
        }
    }
    __syncthreads();
    float h = Hin[ch][dl];
    float* smp = smoothed + ((size_t)b * M_ + ch * 64) * D_ + d0 + dl;
    #pragma unroll 8
    for (int i = 0; i < 64; ++i) {
        int m = ch * 64 + i;
        float c = ctp[(size_t)i * D_];
        h = ad[m] * h + bdp[m] * c;
        smp[(size_t)i * D_] = h;
    }
}

// ---------------- plug_back_idx = clip(cumsum(probs>=0.5)-1, 0) ----------------
__global__ void pbi_kernel(const float* __restrict__ probs, int* __restrict__ pbi) {
    int b = blockIdx.x;
    int t = threadIdx.x;
    __shared__ int part[256];
    int base = b * L_ + t * 16;
    int cnt[16];
    int s = 0;
    #pragma unroll
    for (int i = 0; i < 16; ++i) {
        s += (probs[base + i] >= 0.5f) ? 1 : 0;
        cnt[i] = s;
    }
    part[t] = s;
    __syncthreads();
    for (int off = 1; off < 256; off <<= 1) {
        int x = part[t];
        int y = (t >= off) ? part[t - off] : 0;
        __syncthreads();
        part[t] = x + y;
        __syncthreads();
    }
    int excl = part[t] - s;
    #pragma unroll
    for (int i = 0; i < 16; ++i) {
        int v = excl + cnt[i] - 1;
        pbi[base + i] = v > 0 ? v : 0;
    }
}

// ---------------- GEMM (m97 structure): bf16 A,B via global_load_lds, fused epilogue ----------------
// BM=BN=128, BK=64, 4 waves (2x2), 16x16x32 MFMA, linear LDS (no swizzle: T2 null at 128²+2ph)
__global__ __launch_bounds__(256, 2) void gemm_kernel(
    const unsigned short* __restrict__ encb, const unsigned short* __restrict__ Wb,
    const float* __restrict__ smoothed, const int* __restrict__ pbi,
    float* __restrict__ out)
{
    __shared__ __align__(16) unsigned short As[128 * 64];
    __shared__ __align__(16) unsigned short Bs[128 * 64];

    const int tid  = threadIdx.x;
    const int lane = tid & 63;
    const int w    = tid >> 6;
    const int wm   = w >> 1;
    const int wn   = w & 1;
    const int l15  = lane & 15;
    const int l16  = lane >> 4;

    const size_t rowBase = (size_t)blockIdx.x * 128;
    const int    colBase = blockIdx.y * 128;

    const int srow = lane >> 3;        // 0..7
    const int scol = (lane & 7) * 8;   // 0..56

    const unsigned short* aSrc = encb + (rowBase + srow) * D_ + scol;
    const unsigned short* bSrc = Wb + ((size_t)colBase + srow) * D_ + scol;

    f32x4 acc[4][4] = {};

    for (int t = 0; t < D_ / 64; ++t) {
        const int k0 = t * 64;
        #pragma unroll
        for (int i = 0; i < 4; ++i) {
            int seg = w * 4 + i;       // 0..15, covers 8 rows each
            __builtin_amdgcn_global_load_lds(
                (const __attribute__((address_space(1))) void*)(aSrc + (size_t)seg * 8 * D_ + k0),
                (__attribute__((address_space(3))) void*)(&As[seg * 512]), 16, 0, 0);
            __builtin_amdgcn_global_load_lds(
                (const __attribute__((address_space(1))) void*)(bSrc + (size_t)seg * 8 * D_ + k0),
                (__attribute__((address_space(3))) void*)(&Bs[seg * 512]), 16, 0, 0);
        }
        __syncthreads();
        #pragma unroll
        for (int kk = 0; kk < 2; ++kk) {
            bf16x8 a[4], bb[4];
            #pragma unroll
            for (int m = 0; m < 4; ++m)
                a[m] = *(const bf16x8*)&As[(wm * 64 + m * 16 + l15) * 64 + kk * 32 + l16 * 8];
            #pragma unroll
            for (int n = 0; n < 4; ++n)
                bb[n] = *(const bf16x8*)&Bs[(wn * 64 + n * 16 + l15) * 64 + kk * 32 + l16 * 8];
            #pragma unroll
            for (int m = 0; m < 4; ++m)
                #pragma unroll
                for (int n = 0; n < 4; ++n)
                    acc[m][n] = __builtin_amdgcn_mfma_f32_16x16x32_bf16(a[m], bb[n], acc[m][n], 0, 0, 0);
        }
        __syncthreads();
    }

    #pragma unroll
    for (int m = 0; m < 4; ++m) {
        #pragma unroll
        for (int j = 0; j < 4; ++j) {
            size_t row = rowBase + wm * 64 + m * 16 + l16 * 4 + j;
            int b  = (int)(row >> 12);
            int pb = pbi[row];
            pb = pb < (M_ - 1) ? pb : (M_ - 1);
            const float* sm = smoothed + ((size_t)(b * M_ + pb)) * D_;
            #pragma unroll
            for (int n = 0; n < 4; ++n) {
                int col = colBase + wn * 64 + n * 16 + l15;
                out[row * D_ + col] = acc[m][n][j] + sm[col];
            }
        }
    }
}

// ---------------- fallback fused-convert GEMM (R0 version) if ws is small ----------------
#define LDP 72
__global__ __launch_bounds__(256, 2) void gemm_fused_kernel(
    const float* __restrict__ enc, const unsigned short* __restrict__ Wb,
    const float* __restrict__ smoothed, const int* __restrict__ pbi,
    float* __restrict__ out)
{
    __shared__ unsigned short As[128][LDP];
    __shared__ unsigned short Bs[128][LDP];
    const int tid  = threadIdx.x;
    const int lane = tid & 63;
    const int wid  = tid >> 6;
    const int wm   = wid >> 1;
    const int wn   = wid & 1;
    const int l15  = lane & 15;
    const int l16  = lane >> 4;
    const size_t rowBase = (size_t)blockIdx.x * 128;
    const int    colBase = blockIdx.y * 128;
    f32x4 acc[4][4] = {};
    for (int t = 0; t < D_ / 64; ++t) {
        const int k0 = t * 64;
        #pragma unroll
        for (int i = 0; i < 4; ++i) {
            int c = i * 256 + tid;
            int r = c >> 3;
            int c8 = c & 7;
            const float4* g = (const float4*)(enc + (rowBase + r) * D_ + k0 + c8 * 8);
            float4 x0 = g[0];
            float4 x1 = g[1];
            u16x8 v;
            v[0] = f2bf(x0.x); v[1] = f2bf(x0.y); v[2] = f2bf(x0.z); v[3] = f2bf(x0.w);
            v[4] = f2bf(x1.x); v[5] = f2bf(x1.y); v[6] = f2bf(x1.z); v[7] = f2bf(x1.w);
            *(u16x8*)&As[r][c8 * 8] = v;
        }
        #pragma unroll
        for (int i = 0; i < 4; ++i) {
            int c = i * 256 + tid;
            int r = c >> 3;
            int c8 = c & 7;
            u16x8 v = *(const u16x8*)(Wb + (size_t)(colBase + r) * D_ + k0 + c8 * 8);
            *(u16x8*)&Bs[r][c8 * 8] = v;
        }
        __syncthreads();
        #pragma unroll
        for (int kk = 0; kk < 2; ++kk) {
            bf16x8 a[4], bb[4];
            #pragma unroll
            for (int m = 0; m < 4; ++m)
                a[m] = *(const bf16x8*)&As[wm * 64 + m * 16 + l15][kk * 32 + l16 * 8];
            #pragma unroll
            for (int n = 0; n < 4; ++n)
                bb[n] = *(const bf16x8*)&Bs[wn * 64 + n * 16 + l15][kk * 32 + l16 * 8];
            #pragma unroll
            for (int m = 0; m < 4; ++m)
                #pragma unroll
                for (int n = 0; n < 4; ++n)
                    acc[m][n] = __builtin_amdgcn_mfma_f32_16x16x32_bf16(a[m], bb[n], acc[m][n], 0, 0, 0);
        }
        __syncthreads();
    }
    #pragma unroll
    for (int m = 0; m < 4; ++m) {
        #pragma unroll
        for (int j = 0; j < 4; ++j) {
            size_t row = rowBase + wm * 64 + m * 16 + l16 * 4 + j;
            int b  = (int)(row >> 12);
            int pb = pbi[row];
            pb = pb < (M_ - 1) ? pb : (M_ - 1);
            const float* sm = smoothed + ((size_t)(b * M_ + pb)) * D_;
            #pragma unroll
            for (int n = 0; n < 4; ++n) {
                int col = colBase + wn * 64 + n * 16 + l15;
                out[row * D_ + col] = acc[m][n][j] + sm[col];
            }
        }
    }
}

extern "C" void kernel_launch(void* const* d_in, const int* in_sizes, int n_in,
                              void* d_out, int out_size, void* d_ws, size_t ws_size,
                              hipStream_t stream) {
    const float* ct    = (const float*)d_in[0];
    const float* enc   = (const float*)d_in[1];
    const float* probs = (const float*)d_in[2];
    const int*   bidx  = (const int*)d_in[3];
    const float* W     = (const float*)d_in[5];
    float* out = (float*)d_out;
    char*  ws  = (char*)d_ws;

    const size_t SZ_ENCB = (size_t)B_ * L_ * D_ * 2;   // 32 MiB
    const size_t SZ_SM   = (size_t)B_ * M_ * D_ * 4;   // 8 MiB
    const size_t SZ_PBI  = (size_t)B_ * L_ * 4;        // 64 KiB
    const size_t SZ_WB   = (size_t)D_ * D_ * 2;        // 2 MiB

    if (ws_size >= SZ_ENCB + SZ_SM + SZ_PBI + SZ_WB) {
        unsigned short* encb     = (unsigned short*)ws;
        float*          smoothed = (float*)(ws + SZ_ENCB);
        int*            pbi      = (int*)(ws + SZ_ENCB + SZ_SM);
        unsigned short* Wb       = (unsigned short*)(ws + SZ_ENCB + SZ_SM + SZ_PBI);

        hipLaunchKernelGGL(cvt_kernel, dim3(B_ * L_ * D_ / 2048), dim3(256), 0, stream, enc, encb);
        hipLaunchKernelGGL(cvt_kernel, dim3(D_ * D_ / 2048),      dim3(256), 0, stream, W, Wb);
        hipLaunchKernelGGL(ema_kernel, dim3(B_ * D_ / 64),        dim3(512), 0, stream, ct, probs, bidx, smoothed);
        hipLaunchKernelGGL(pbi_kernel, dim3(B_),                  dim3(256), 0, stream, probs, pbi);
        hipLaunchKernelGGL(gemm_kernel, dim3(B_ * L_ / 128, D_ / 128), dim3(256), 0, stream,
                           encb, Wb, smoothed, pbi, out);
    } else {
        float*          smoothed = (float*)ws;
        int*            pbi      = (int*)(ws + SZ_SM);
        unsigned short* Wb       = (unsigned short*)(ws + SZ_SM + SZ_PBI);
        hipLaunchKernelGGL(cvt_kernel, dim3(D_ * D_ / 2048), dim3(256), 0, stream, W, Wb);
        hipLaunchKernelGGL(ema_kernel, dim3(B_ * D_ / 64),   dim3(512), 0, stream, ct, probs, bidx, smoothed);
        hipLaunchKernelGGL(pbi_kernel, dim3(B_),             dim3(256), 0, stream, probs, pbi);
        hipLaunchKernelGGL(gemm_fused_kernel, dim3(B_ * L_ / 128, D_ / 128), dim3(256), 0, stream,
                           enc, Wb, smoothed, pbi, out);
    }
}

// Round 3
// 177.282 us; speedup vs baseline: 1.3192x; 1.0510x over previous
//
#include <hip/hip_runtime.h>
#include <hip/hip_bf16.h>
#include <stdint.h>

// B=4, L=4096, D=1024, M_MAX=512
// out[b,l,e] = smoothed[b, pbi[b,l], e] + sum_d enc[b,l,d] * W[e,d]

#define B_  4
#define L_  4096
#define D_  1024
#define M_  512

typedef __attribute__((ext_vector_type(8))) short bf16x8;
typedef __attribute__((ext_vector_type(4))) float f32x4;
typedef __attribute__((ext_vector_type(8))) unsigned short u16x8;

__device__ inline unsigned short f2bf(float f) {
    unsigned u = __float_as_uint(f);
    u += 0x7fffu + ((u >> 16) & 1u);   // RNE
    return (unsigned short)(u >> 16);
}

// ============ prep: cvt(enc)+cvt(W)+pbi in one launch ============
// blocks [0,8192): enc f32->bf16 ; [8192,8704): W f32->bf16 ; [8704,8708): pbi
__global__ void prep_kernel(const float* __restrict__ enc, const float* __restrict__ W,
                            const float* __restrict__ probs,
                            unsigned short* __restrict__ encb, unsigned short* __restrict__ Wb,
                            int* __restrict__ pbi) {
    __shared__ int part[256];
    int blk = blockIdx.x;
    int tid = threadIdx.x;
    if (blk < 8704) {
        const float* src; unsigned short* dst; int i;
        if (blk < 8192) { src = enc; dst = encb; i = blk * 256 + tid; }
        else            { src = W;   dst = Wb;   i = (blk - 8192) * 256 + tid; }
        float4 x0 = ((const float4*)src)[2 * i];
        float4 x1 = ((const float4*)src)[2 * i + 1];
        u16x8 v;
        v[0] = f2bf(x0.x); v[1] = f2bf(x0.y); v[2] = f2bf(x0.z); v[3] = f2bf(x0.w);
        v[4] = f2bf(x1.x); v[5] = f2bf(x1.y); v[6] = f2bf(x1.z); v[7] = f2bf(x1.w);
        ((u16x8*)dst)[i] = v;
    } else {
        int b = blk - 8704;
        const float4* pr = (const float4*)(probs + b * L_);
        int cnt[16]; int s = 0;
        #pragma unroll
        for (int u = 0; u < 4; ++u) {
            float4 x = pr[tid * 4 + u];
            s += (x.x >= 0.5f); cnt[u * 4 + 0] = s;
            s += (x.y >= 0.5f); cnt[u * 4 + 1] = s;
            s += (x.z >= 0.5f); cnt[u * 4 + 2] = s;
            s += (x.w >= 0.5f); cnt[u * 4 + 3] = s;
        }
        part[tid] = s;
        __syncthreads();
        for (int off = 1; off < 256; off <<= 1) {
            int x = part[tid];
            int y = (tid >= off) ? part[tid - off] : 0;
            __syncthreads();
            part[tid] = x + y;
            __syncthreads();
        }
        int excl = part[tid] - s;
        int4* po = (int4*)(pbi + b * L_ + tid * 16);
        #pragma unroll
        for (int u = 0; u < 4; ++u) {
            int4 o;
            o.x = max(excl + cnt[u * 4 + 0] - 1, 0);
            o.y = max(excl + cnt[u * 4 + 1] - 1, 0);
            o.z = max(excl + cnt[u * 4 + 2] - 1, 0);
            o.w = max(excl + cnt[u * 4 + 3] - 1, 0);
            po[u] = o;
        }
    }
}

// ============ EMA: chunk summaries (A,B) per (b, ch, d) ============
// grid dim3(D/256, 8, B), 256 threads
__global__ void ema1_kernel(const float* __restrict__ ct, const float* __restrict__ probs,
                            const int* __restrict__ bidx, float2* __restrict__ summ) {
    int b = blockIdx.z, ch = blockIdx.y;
    int d = blockIdx.x * 256 + threadIdx.x;
    __shared__ float pa[64], pb[64];
    if (threadIdx.x < 64) {
        int m = ch * 64 + threadIdx.x;
        int idx = bidx[b * M_ + m];
        float pv = fmaxf(probs[b * L_ + idx], 0.1f);
        pa[threadIdx.x] = (m == 0) ? 0.0f : fmaxf(1.0f - pv, 1e-7f);
        pb[threadIdx.x] = (m == 0) ? 1.0f : pv;
    }
    __syncthreads();
    const float* ctp = ct + ((size_t)b * M_ + ch * 64) * D_ + d;
    float A = 1.0f, Bv = 0.0f;
    #pragma unroll 8
    for (int i = 0; i < 64; ++i) {
        float c = ctp[(size_t)i * D_];
        A  = pa[i] * A;
        Bv = pa[i] * Bv + pb[i] * c;
    }
    summ[((size_t)b * 8 + ch) * D_ + d] = make_float2(A, Bv);
}

// ============ EMA: apply (prefix over chunk summaries, then scan) ============
__global__ void ema2_kernel(const float* __restrict__ ct, const float* __restrict__ probs,
                            const int* __restrict__ bidx, const float2* __restrict__ summ,
                            float* __restrict__ smoothed) {
    int b = blockIdx.z, ch = blockIdx.y;
    int d = blockIdx.x * 256 + threadIdx.x;
    __shared__ float pa[64], pb[64];
    if (threadIdx.x < 64) {
        int m = ch * 64 + threadIdx.x;
        int idx = bidx[b * M_ + m];
        float pv = fmaxf(probs[b * L_ + idx], 0.1f);
        pa[threadIdx.x] = (m == 0) ? 0.0f : fmaxf(1.0f - pv, 1e-7f);
        pb[threadIdx.x] = (m == 0) ? 1.0f : pv;
    }
    __syncthreads();
    float h = 0.0f;
    for (int c = 0; c < ch; ++c) {      // block-uniform loop
        float2 s2 = summ[((size_t)b * 8 + c) * D_ + d];
        h = s2.x * h + s2.y;
    }
    const float* ctp = ct + ((size_t)b * M_ + ch * 64) * D_ + d;
    float*       smp = smoothed + ((size_t)b * M_ + ch * 64) * D_ + d;
    #pragma unroll 8
    for (int i = 0; i < 64; ++i) {
        float c = ctp[(size_t)i * D_];
        h = pa[i] * h + pb[i] * c;
        smp[(size_t)i * D_] = h;
    }
}

// ============ GEMM: 256x256, BK=32, 3-buffer counted-vmcnt pipeline ============
// 512 thr = 8 waves (2M x 4N); per-wave 128x64 out = 8x4 16x16 frags.
// LDS 96 KiB: 3 x (A 256x32 + B 256x32) bf16, 64-B rows, XOR swizzle on col bits4-5 by row&3.
#define NT_ 32   // K tiles

__global__ __launch_bounds__(512, 1) void gemm3_kernel(
    const unsigned short* __restrict__ encb, const unsigned short* __restrict__ Wb,
    const float* __restrict__ smoothed, const int* __restrict__ pbi,
    float* __restrict__ out)
{
    __shared__ __align__(16) unsigned short As[3][256 * 32];
    __shared__ __align__(16) unsigned short Bs[3][256 * 32];

    const int tid  = threadIdx.x;
    const int lane = tid & 63;
    const int w    = tid >> 6;        // 0..7
    const int wm   = w >> 2;          // 0..1
    const int wn   = w & 3;           // 0..3
    const int l15  = lane & 15;
    const int l16  = lane >> 4;

    // bijective XCD swizzle (256 blocks, 8 XCDs): XCD x owns M-panels [x*8, x*8+8)
    const int orig = blockIdx.x;
    const int rm   = (orig & 7) * 32 + (orig >> 3);
    const size_t rowBase = (size_t)(rm >> 2) * 256;
    const int    colBase = (rm & 3) * 256;

    // stage source pre-swizzle: lane writes LDS lin (row=lane>>2, colb=(lane&3)*16);
    // source col bytes = colb ^ ((row&3)<<4)
    const int rsw = (((lane & 3) ^ ((lane >> 2) & 3)) << 3);   // in elements

#define STAGE(kt, s)                                                                     \
  {                                                                                      \
    _Pragma("unroll")                                                                    \
    for (int i_ = 0; i_ < 2; ++i_) {                                                     \
      int row_ = i_ * 128 + w * 16 + (lane >> 2);                                        \
      const unsigned short* ga_ = encb + (rowBase + row_) * D_ + (kt) * 32 + rsw;        \
      __builtin_amdgcn_global_load_lds(                                                  \
          (const __attribute__((address_space(1))) void*)ga_,                            \
          (__attribute__((address_space(3))) void*)&As[s][i_ * 4096 + w * 512], 16, 0, 0);\
      const unsigned short* gb_ = Wb + (size_t)(colBase + row_) * D_ + (kt) * 32 + rsw;  \
      __builtin_amdgcn_global_load_lds(                                                  \
          (const __attribute__((address_space(1))) void*)gb_,                            \
          (__attribute__((address_space(3))) void*)&Bs[s][i_ * 4096 + w * 512], 16, 0, 0);\
    }                                                                                    \
  }

    f32x4 acc[8][4] = {};

    STAGE(0, 0);
    STAGE(1, 1);
    asm volatile("s_waitcnt vmcnt(4)" ::: "memory");   // tile0's 4 loads done (per-wave); +barrier => all waves
    __builtin_amdgcn_s_barrier();
    __builtin_amdgcn_sched_barrier(0);

    int s = 0;
    for (int t = 0; t < NT_; ++t) {
        const char* aB = (const char*)As[s];
        const char* bB = (const char*)Bs[s];
        const int swz = (l15 & 3) << 4;
        bf16x8 a[8], bb[4];
        #pragma unroll
        for (int m = 0; m < 8; ++m)
            a[m] = *(const bf16x8*)(aB + (wm * 128 + m * 16 + l15) * 64 + ((l16 * 16) ^ swz));
        #pragma unroll
        for (int n = 0; n < 4; ++n)
            bb[n] = *(const bf16x8*)(bB + (wn * 64 + n * 16 + l15) * 64 + ((l16 * 16) ^ swz));

        int s2 = s + 2; if (s2 >= 3) s2 -= 3;
        if (t + 2 < NT_) STAGE(t + 2, s2);            // writes buf consumed at tile t-1 (safe after boundary barrier)

        __builtin_amdgcn_s_setprio(1);
        #pragma unroll
        for (int m = 0; m < 8; ++m)
            #pragma unroll
            for (int n = 0; n < 4; ++n)
                acc[m][n] = __builtin_amdgcn_mfma_f32_16x16x32_bf16(a[m], bb[n], acc[m][n], 0, 0, 0);
        __builtin_amdgcn_s_setprio(0);

        if (t + 1 < NT_) {
            // need tile t+1 landed: newest 4 outstanding are t+2's (if staged) -> counted wait
            if (t + 2 < NT_) { asm volatile("s_waitcnt vmcnt(4)" ::: "memory"); }
            else             { asm volatile("s_waitcnt vmcnt(0)" ::: "memory"); }
            __builtin_amdgcn_s_barrier();
            __builtin_amdgcn_sched_barrier(0);
        }
        s += 1; if (s >= 3) s -= 3;
    }
#undef STAGE

    // epilogue: fused plugback gather + add, fp32 store
    #pragma unroll
    for (int m = 0; m < 8; ++m) {
        const size_t row0 = rowBase + wm * 128 + m * 16;
        #pragma unroll
        for (int j = 0; j < 4; ++j) {
            size_t row = row0 + l16 * 4 + j;
            int b  = (int)(row >> 12);
            int pb = pbi[row];
            pb = pb < (M_ - 1) ? pb : (M_ - 1);
            const float* sm = smoothed + ((size_t)(b * M_ + pb)) * D_;
            #pragma unroll
            for (int n = 0; n < 4; ++n) {
                int col = colBase + wn * 64 + n * 16 + l15;
                out[row * D_ + col] = acc[m][n][j] + sm[col];
            }
        }
    }
}

// ---------------- fallback fused-convert GEMM (proven R1 path) if ws too small ----------------
#define LDP 72
__global__ __launch_bounds__(256, 2) void gemm_fused_kernel(
    const float* __restrict__ enc, const unsigned short* __restrict__ Wb,
    const float* __restrict__ smoothed, const int* __restrict__ pbi,
    float* __restrict__ out)
{
    __shared__ unsigned short Asf[128][LDP];
    __shared__ unsigned short Bsf[128][LDP];
    const int tid  = threadIdx.x;
    const int lane = tid & 63;
    const int wid  = tid >> 6;
    const int wm   = wid >> 1;
    const int wn   = wid & 1;
    const int l15  = lane & 15;
    const int l16  = lane >> 4;
    const size_t rowBase = (size_t)blockIdx.x * 128;
    const int    colBase = blockIdx.y * 128;
    f32x4 acc[4][4] = {};
    for (int t = 0; t < D_ / 64; ++t) {
        const int k0 = t * 64;
        #pragma unroll
        for (int i = 0; i < 4; ++i) {
            int c = i * 256 + tid;
            int r = c >> 3;
            int c8 = c & 7;
            const float4* g = (const float4*)(enc + (rowBase + r) * D_ + k0 + c8 * 8);
            float4 x0 = g[0];
            float4 x1 = g[1];
            u16x8 v;
            v[0] = f2bf(x0.x); v[1] = f2bf(x0.y); v[2] = f2bf(x0.z); v[3] = f2bf(x0.w);
            v[4] = f2bf(x1.x); v[5] = f2bf(x1.y); v[6] = f2bf(x1.z); v[7] = f2bf(x1.w);
            *(u16x8*)&Asf[r][c8 * 8] = v;
        }
        #pragma unroll
        for (int i = 0; i < 4; ++i) {
            int c = i * 256 + tid;
            int r = c >> 3;
            int c8 = c & 7;
            u16x8 v = *(const u16x8*)(Wb + (size_t)(colBase + r) * D_ + k0 + c8 * 8);
            *(u16x8*)&Bsf[r][c8 * 8] = v;
        }
        __syncthreads();
        #pragma unroll
        for (int kk = 0; kk < 2; ++kk) {
            bf16x8 a[4], bbf[4];
            #pragma unroll
            for (int m = 0; m < 4; ++m)
                a[m] = *(const bf16x8*)&Asf[wm * 64 + m * 16 + l15][kk * 32 + l16 * 8];
            #pragma unroll
            for (int n = 0; n < 4; ++n)
                bbf[n] = *(const bf16x8*)&Bsf[wn * 64 + n * 16 + l15][kk * 32 + l16 * 8];
            #pragma unroll
            for (int m = 0; m < 4; ++m)
                #pragma unroll
                for (int n = 0; n < 4; ++n)
                    acc[m][n] = __builtin_amdgcn_mfma_f32_16x16x32_bf16(a[m], bbf[n], acc[m][n], 0, 0, 0);
        }
        __syncthreads();
    }
    #pragma unroll
    for (int m = 0; m < 4; ++m) {
        #pragma unroll
        for (int j = 0; j < 4; ++j) {
            size_t row = rowBase + wm * 64 + m * 16 + l16 * 4 + j;
            int b  = (int)(row >> 12);
            int pb = pbi[row];
            pb = pb < (M_ - 1) ? pb : (M_ - 1);
            const float* sm = smoothed + ((size_t)(b * M_ + pb)) * D_;
            #pragma unroll
            for (int n = 0; n < 4; ++n) {
                int col = colBase + wn * 64 + n * 16 + l15;
                out[row * D_ + col] = acc[m][n][j] + sm[col];
            }
        }
    }
}

extern "C" void kernel_launch(void* const* d_in, const int* in_sizes, int n_in,
                              void* d_out, int out_size, void* d_ws, size_t ws_size,
                              hipStream_t stream) {
    const float* ct    = (const float*)d_in[0];
    const float* enc   = (const float*)d_in[1];
    const float* probs = (const float*)d_in[2];
    const int*   bidx  = (const int*)d_in[3];
    const float* W     = (const float*)d_in[5];
    float* out = (float*)d_out;
    char*  ws  = (char*)d_ws;

    const size_t SZ_ENCB = (size_t)B_ * L_ * D_ * 2;   // 32 MiB
    const size_t SZ_SM   = (size_t)B_ * M_ * D_ * 4;   // 8 MiB
    const size_t SZ_PBI  = (size_t)B_ * L_ * 4;        // 64 KiB
    const size_t SZ_WB   = (size_t)D_ * D_ * 2;        // 2 MiB
    const size_t SZ_SUMM = (size_t)B_ * 8 * D_ * 8;    // 256 KiB

    if (ws_size >= SZ_ENCB + SZ_SM + SZ_PBI + SZ_WB + SZ_SUMM) {
        unsigned short* encb     = (unsigned short*)ws;
        float*          smoothed = (float*)(ws + SZ_ENCB);
        int*            pbi      = (int*)(ws + SZ_ENCB + SZ_SM);
        unsigned short* Wb       = (unsigned short*)(ws + SZ_ENCB + SZ_SM + SZ_PBI);
        float2*         summ     = (float2*)(ws + SZ_ENCB + SZ_SM + SZ_PBI + SZ_WB);

        hipLaunchKernelGGL(prep_kernel, dim3(8708), dim3(256), 0, stream,
                           enc, W, probs, encb, Wb, pbi);
        hipLaunchKernelGGL(ema1_kernel, dim3(D_ / 256, 8, B_), dim3(256), 0, stream,
                           ct, probs, bidx, summ);
        hipLaunchKernelGGL(ema2_kernel, dim3(D_ / 256, 8, B_), dim3(256), 0, stream,
                           ct, probs, bidx, summ, smoothed);
        hipLaunchKernelGGL(gemm3_kernel, dim3(256), dim3(512), 0, stream,
                           encb, Wb, smoothed, pbi, out);
    } else {
        // fallback: fused-convert GEMM path (needs 10.3 MiB)
        float*          smoothed = (float*)ws;
        int*            pbi      = (int*)(ws + SZ_SM);
        unsigned short* Wb       = (unsigned short*)(ws + SZ_SM + SZ_PBI);
        float2*         summ     = (float2*)(ws + SZ_SM + SZ_PBI + SZ_WB);
        hipLaunchKernelGGL(prep_kernel, dim3(8708), dim3(256), 0, stream,
                           enc, W, probs, (unsigned short*)summ /*unused dst, W only*/, Wb, pbi);
        hipLaunchKernelGGL(ema1_kernel, dim3(D_ / 256, 8, B_), dim3(256), 0, stream,
                           ct, probs, bidx, summ);
        hipLaunchKernelGGL(ema2_kernel, dim3(D_ / 256, 8, B_), dim3(256), 0, stream,
                           ct, probs, bidx, summ, smoothed);
        hipLaunchKernelGGL(gemm_fused_kernel, dim3(B_ * L_ / 128, D_ / 128), dim3(256), 0, stream,
                           enc, Wb, smoothed, pbi, out);
    }
}

// Round 4
// 171.082 us; speedup vs baseline: 1.3670x; 1.0362x over previous
//
#include <hip/hip_runtime.h>
#include <hip/hip_bf16.h>
#include <stdint.h>

// B=4, L=4096, D=1024, M_MAX=512
// out[b,l,e] = smoothed[b, pbi[b,l], e] + sum_d enc[b,l,d] * W[e,d]

#define B_  4
#define L_  4096
#define D_  1024
#define M_  512

typedef __attribute__((ext_vector_type(8))) short bf16x8;
typedef __attribute__((ext_vector_type(4))) float f32x4;
typedef __attribute__((ext_vector_type(8))) unsigned short u16x8;

__device__ inline unsigned short f2bf(float f) {
    unsigned u = __float_as_uint(f);
    u += 0x7fffu + ((u >> 16) & 1u);   // RNE
    return (unsigned short)(u >> 16);
}

// ============ prep_all: enc cvt + W cvt + pbi + EMA in ONE launch ============
// 512-thread blocks. Block ranges:
//   [0, EB)            : enc f32->bf16, 8 elems/thread
//   [EB, EB+256)       : W   f32->bf16
//   [EB+256, EB+260)   : pbi  (one block per batch)
//   [EB+260, EB+324)   : EMA  (one block per (b, 64-d slice)), chunked affine scan
__global__ void prep_all_kernel(const float* __restrict__ enc, const float* __restrict__ W,
                                const float* __restrict__ probs, const float* __restrict__ ct,
                                const int* __restrict__ bidx,
                                unsigned short* __restrict__ encb, unsigned short* __restrict__ Wb,
                                int* __restrict__ pbi, float* __restrict__ smoothed,
                                int encBlocks) {
    __shared__ int part[512];
    __shared__ float ad[M_], bdp[M_];
    __shared__ float Ac[8][64], Bc[8][64], Hin[8][64];

    const int blk = blockIdx.x;
    const int t   = threadIdx.x;

    if (blk < encBlocks + 256) {
        // ---- fp32 -> bf16 convert, 8 elems/thread ----
        const float* src; unsigned short* dst; size_t i;
        if (blk < encBlocks) { src = enc; dst = encb; i = (size_t)blk * 512 + t; }
        else                 { src = W;   dst = Wb;   i = (size_t)(blk - encBlocks) * 512 + t; }
        float4 x0 = ((const float4*)src)[2 * i];
        float4 x1 = ((const float4*)src)[2 * i + 1];
        u16x8 v;
        v[0] = f2bf(x0.x); v[1] = f2bf(x0.y); v[2] = f2bf(x0.z); v[3] = f2bf(x0.w);
        v[4] = f2bf(x1.x); v[5] = f2bf(x1.y); v[6] = f2bf(x1.z); v[7] = f2bf(x1.w);
        ((u16x8*)dst)[i] = v;
    } else if (blk < encBlocks + 260) {
        // ---- plug_back_idx = clip(cumsum(probs>=0.5)-1, 0) ----
        int b = blk - (encBlocks + 256);
        const float4* pr = (const float4*)(probs + b * L_);
        int cnt[8]; int s = 0;
        #pragma unroll
        for (int u = 0; u < 2; ++u) {
            float4 x = pr[t * 2 + u];
            s += (x.x >= 0.5f); cnt[u * 4 + 0] = s;
            s += (x.y >= 0.5f); cnt[u * 4 + 1] = s;
            s += (x.z >= 0.5f); cnt[u * 4 + 2] = s;
            s += (x.w >= 0.5f); cnt[u * 4 + 3] = s;
        }
        part[t] = s;
        __syncthreads();
        for (int off = 1; off < 512; off <<= 1) {
            int x = part[t];
            int y = (t >= off) ? part[t - off] : 0;
            __syncthreads();
            part[t] = x + y;
            __syncthreads();
        }
        int excl = part[t] - s;
        int4* po = (int4*)(pbi + b * L_ + t * 8);
        #pragma unroll
        for (int u = 0; u < 2; ++u) {
            int4 o;
            o.x = max(excl + cnt[u * 4 + 0] - 1, 0);
            o.y = max(excl + cnt[u * 4 + 1] - 1, 0);
            o.z = max(excl + cnt[u * 4 + 2] - 1, 0);
            o.w = max(excl + cnt[u * 4 + 3] - 1, 0);
            po[u] = o;
        }
    } else {
        // ---- EMA chunked affine scan: h_m = a_m*h_{m-1} + b_m ----
        int idx = blk - (encBlocks + 260);
        int b  = idx >> 4;
        int d0 = (idx & 15) * 64;
        int dl = t & 63;
        int ch = t >> 6;                      // 0..7 chunks of 64 m's
        {
            int m = t;                         // 512 threads cover M_=512 exactly
            int bi = bidx[b * M_ + m];
            float p = fmaxf(probs[b * L_ + bi], 0.1f);
            ad[m]  = (m == 0) ? 0.0f : fmaxf(1.0f - p, 1e-7f);
            bdp[m] = (m == 0) ? 1.0f : p;
        }
        __syncthreads();
        const float* ctp = ct + ((size_t)b * M_ + ch * 64) * D_ + d0 + dl;
        float A = 1.0f, Bv = 0.0f;
        #pragma unroll 8
        for (int i = 0; i < 64; ++i) {
            int m = ch * 64 + i;
            float c = ctp[(size_t)i * D_];
            A  = ad[m] * A;
            Bv = ad[m] * Bv + bdp[m] * c;
        }
        Ac[ch][dl] = A; Bc[ch][dl] = Bv;
        __syncthreads();
        if (t < 64) {                          // per-d prefix over 8 chunk summaries
            float H = 0.0f;
            #pragma unroll
            for (int c = 0; c < 8; ++c) {
                Hin[c][t] = H;
                H = Ac[c][t] * H + Bc[c][t];
            }
        }
        __syncthreads();
        float h = Hin[ch][dl];
        float* smp = smoothed + ((size_t)b * M_ + ch * 64) * D_ + d0 + dl;
        #pragma unroll 8
        for (int i = 0; i < 64; ++i) {
            int m = ch * 64 + i;
            float c = ctp[(size_t)i * D_];
            h = ad[m] * h + bdp[m] * c;
            smp[(size_t)i * D_] = h;
        }
    }
}

// ============ GEMM: 256x256, BK=32, 3-buffer counted-vmcnt pipeline (R3, unchanged) ============
#define NT_ 32   // K tiles

__global__ __launch_bounds__(512, 1) void gemm3_kernel(
    const unsigned short* __restrict__ encb, const unsigned short* __restrict__ Wb,
    const float* __restrict__ smoothed, const int* __restrict__ pbi,
    float* __restrict__ out)
{
    __shared__ __align__(16) unsigned short As[3][256 * 32];
    __shared__ __align__(16) unsigned short Bs[3][256 * 32];

    const int tid  = threadIdx.x;
    const int lane = tid & 63;
    const int w    = tid >> 6;        // 0..7
    const int wm   = w >> 2;          // 0..1
    const int wn   = w & 3;           // 0..3
    const int l15  = lane & 15;
    const int l16  = lane >> 4;

    const int orig = blockIdx.x;
    const int rm   = (orig & 7) * 32 + (orig >> 3);
    const size_t rowBase = (size_t)(rm >> 2) * 256;
    const int    colBase = (rm & 3) * 256;

    const int rsw = (((lane & 3) ^ ((lane >> 2) & 3)) << 3);   // pre-swizzled source col (elements)

#define STAGE(kt, s)                                                                     \
  {                                                                                      \
    _Pragma("unroll")                                                                    \
    for (int i_ = 0; i_ < 2; ++i_) {                                                     \
      int row_ = i_ * 128 + w * 16 + (lane >> 2);                                        \
      const unsigned short* ga_ = encb + (rowBase + row_) * D_ + (kt) * 32 + rsw;        \
      __builtin_amdgcn_global_load_lds(                                                  \
          (const __attribute__((address_space(1))) void*)ga_,                            \
          (__attribute__((address_space(3))) void*)&As[s][i_ * 4096 + w * 512], 16, 0, 0);\
      const unsigned short* gb_ = Wb + (size_t)(colBase + row_) * D_ + (kt) * 32 + rsw;  \
      __builtin_amdgcn_global_load_lds(                                                  \
          (const __attribute__((address_space(1))) void*)gb_,                            \
          (__attribute__((address_space(3))) void*)&Bs[s][i_ * 4096 + w * 512], 16, 0, 0);\
    }                                                                                    \
  }

    f32x4 acc[8][4] = {};

    STAGE(0, 0);
    STAGE(1, 1);
    asm volatile("s_waitcnt vmcnt(4)" ::: "memory");
    __builtin_amdgcn_s_barrier();
    __builtin_amdgcn_sched_barrier(0);

    int s = 0;
    for (int t = 0; t < NT_; ++t) {
        const char* aB = (const char*)As[s];
        const char* bB = (const char*)Bs[s];
        const int swz = (l15 & 3) << 4;
        bf16x8 a[8], bb[4];
        #pragma unroll
        for (int m = 0; m < 8; ++m)
            a[m] = *(const bf16x8*)(aB + (wm * 128 + m * 16 + l15) * 64 + ((l16 * 16) ^ swz));
        #pragma unroll
        for (int n = 0; n < 4; ++n)
            bb[n] = *(const bf16x8*)(bB + (wn * 64 + n * 16 + l15) * 64 + ((l16 * 16) ^ swz));

        int s2 = s + 2; if (s2 >= 3) s2 -= 3;
        if (t + 2 < NT_) STAGE(t + 2, s2);

        __builtin_amdgcn_s_setprio(1);
        #pragma unroll
        for (int m = 0; m < 8; ++m)
            #pragma unroll
            for (int n = 0; n < 4; ++n)
                acc[m][n] = __builtin_amdgcn_mfma_f32_16x16x32_bf16(a[m], bb[n], acc[m][n], 0, 0, 0);
        __builtin_amdgcn_s_setprio(0);

        if (t + 1 < NT_) {
            if (t + 2 < NT_) { asm volatile("s_waitcnt vmcnt(4)" ::: "memory"); }
            else             { asm volatile("s_waitcnt vmcnt(0)" ::: "memory"); }
            __builtin_amdgcn_s_barrier();
            __builtin_amdgcn_sched_barrier(0);
        }
        s += 1; if (s >= 3) s -= 3;
    }
#undef STAGE

    #pragma unroll
    for (int m = 0; m < 8; ++m) {
        const size_t row0 = rowBase + wm * 128 + m * 16;
        #pragma unroll
        for (int j = 0; j < 4; ++j) {
            size_t row = row0 + l16 * 4 + j;
            int b  = (int)(row >> 12);
            int pb = pbi[row];
            pb = pb < (M_ - 1) ? pb : (M_ - 1);
            const float* sm = smoothed + ((size_t)(b * M_ + pb)) * D_;
            #pragma unroll
            for (int n = 0; n < 4; ++n) {
                int col = colBase + wn * 64 + n * 16 + l15;
                out[row * D_ + col] = acc[m][n][j] + sm[col];
            }
        }
    }
}

// ---------------- fallback fused-convert GEMM (if ws too small; unlikely path) ----------------
#define LDP 72
__global__ __launch_bounds__(256, 2) void gemm_fused_kernel(
    const float* __restrict__ enc, const unsigned short* __restrict__ Wb,
    const float* __restrict__ smoothed, const int* __restrict__ pbi,
    float* __restrict__ out)
{
    __shared__ unsigned short Asf[128][LDP];
    __shared__ unsigned short Bsf[128][LDP];
    const int tid  = threadIdx.x;
    const int lane = tid & 63;
    const int wid  = tid >> 6;
    const int wm   = wid >> 1;
    const int wn   = wid & 1;
    const int l15  = lane & 15;
    const int l16  = lane >> 4;
    const size_t rowBase = (size_t)blockIdx.x * 128;
    const int    colBase = blockIdx.y * 128;
    f32x4 acc[4][4] = {};
    for (int t = 0; t < D_ / 64; ++t) {
        const int k0 = t * 64;
        #pragma unroll
        for (int i = 0; i < 4; ++i) {
            int c = i * 256 + tid;
            int r = c >> 3;
            int c8 = c & 7;
            const float4* g = (const float4*)(enc + (rowBase + r) * D_ + k0 + c8 * 8);
            float4 x0 = g[0];
            float4 x1 = g[1];
            u16x8 v;
            v[0] = f2bf(x0.x); v[1] = f2bf(x0.y); v[2] = f2bf(x0.z); v[3] = f2bf(x0.w);
            v[4] = f2bf(x1.x); v[5] = f2bf(x1.y); v[6] = f2bf(x1.z); v[7] = f2bf(x1.w);
            *(u16x8*)&Asf[r][c8 * 8] = v;
        }
        #pragma unroll
        for (int i = 0; i < 4; ++i) {
            int c = i * 256 + tid;
            int r = c >> 3;
            int c8 = c & 7;
            u16x8 v = *(const u16x8*)(Wb + (size_t)(colBase + r) * D_ + k0 + c8 * 8);
            *(u16x8*)&Bsf[r][c8 * 8] = v;
        }
        __syncthreads();
        #pragma unroll
        for (int kk = 0; kk < 2; ++kk) {
            bf16x8 a[4], bbf[4];
            #pragma unroll
            for (int m = 0; m < 4; ++m)
                a[m] = *(const bf16x8*)&Asf[wm * 64 + m * 16 + l15][kk * 32 + l16 * 8];
            #pragma unroll
            for (int n = 0; n < 4; ++n)
                bbf[n] = *(const bf16x8*)&Bsf[wn * 64 + n * 16 + l15][kk * 32 + l16 * 8];
            #pragma unroll
            for (int m = 0; m < 4; ++m)
                #pragma unroll
                for (int n = 0; n < 4; ++n)
                    acc[m][n] = __builtin_amdgcn_mfma_f32_16x16x32_bf16(a[m], bbf[n], acc[m][n], 0, 0, 0);
        }
        __syncthreads();
    }
    #pragma unroll
    for (int m = 0; m < 4; ++m) {
        #pragma unroll
        for (int j = 0; j < 4; ++j) {
            size_t row = rowBase + wm * 64 + m * 16 + l16 * 4 + j;
            int b  = (int)(row >> 12);
            int pb = pbi[row];
            pb = pb < (M_ - 1) ? pb : (M_ - 1);
            const float* sm = smoothed + ((size_t)(b * M_ + pb)) * D_;
            #pragma unroll
            for (int n = 0; n < 4; ++n) {
                int col = colBase + wn * 64 + n * 16 + l15;
                out[row * D_ + col] = acc[m][n][j] + sm[col];
            }
        }
    }
}

extern "C" void kernel_launch(void* const* d_in, const int* in_sizes, int n_in,
                              void* d_out, int out_size, void* d_ws, size_t ws_size,
                              hipStream_t stream) {
    const float* ct    = (const float*)d_in[0];
    const float* enc   = (const float*)d_in[1];
    const float* probs = (const float*)d_in[2];
    const int*   bidx  = (const int*)d_in[3];
    const float* W     = (const float*)d_in[5];
    float* out = (float*)d_out;
    char*  ws  = (char*)d_ws;

    const size_t SZ_ENCB = (size_t)B_ * L_ * D_ * 2;   // 32 MiB
    const size_t SZ_SM   = (size_t)B_ * M_ * D_ * 4;   // 8 MiB
    const size_t SZ_PBI  = (size_t)B_ * L_ * 4;        // 64 KiB
    const size_t SZ_WB   = (size_t)D_ * D_ * 2;        // 2 MiB

    if (ws_size >= SZ_ENCB + SZ_SM + SZ_PBI + SZ_WB) {
        unsigned short* encb     = (unsigned short*)ws;
        float*          smoothed = (float*)(ws + SZ_ENCB);
        int*            pbi      = (int*)(ws + SZ_ENCB + SZ_SM);
        unsigned short* Wb       = (unsigned short*)(ws + SZ_ENCB + SZ_SM + SZ_PBI);

        const int encBlocks = B_ * L_ * D_ / 4096;   // 4096
        const int nBlocks   = encBlocks + 256 + B_ + B_ * D_ / 64;  // 4420
        hipLaunchKernelGGL(prep_all_kernel, dim3(nBlocks), dim3(512), 0, stream,
                           enc, W, probs, ct, bidx, encb, Wb, pbi, smoothed, encBlocks);
        hipLaunchKernelGGL(gemm3_kernel, dim3(256), dim3(512), 0, stream,
                           encb, Wb, smoothed, pbi, out);
    } else {
        // small-ws fallback: skip enc conversion, fused-convert GEMM
        float*          smoothed = (float*)ws;
        int*            pbi      = (int*)(ws + SZ_SM);
        unsigned short* Wb       = (unsigned short*)(ws + SZ_SM + SZ_PBI);
        const int nBlocks = 0 + 256 + B_ + B_ * D_ / 64;
        hipLaunchKernelGGL(prep_all_kernel, dim3(nBlocks), dim3(512), 0, stream,
                           enc, W, probs, ct, bidx, (unsigned short*)ws /*unused*/, Wb, pbi, smoothed, 0);
        hipLaunchKernelGGL(gemm_fused_kernel, dim3(B_ * L_ / 128, D_ / 128), dim3(256), 0, stream,
                           enc, Wb, smoothed, pbi, out);
    }
}